// Round 4
// baseline (480.002 us; speedup 1.0000x reference)
//
#include <hip/hip_runtime.h>
#include <hip/hip_bf16.h>

#define N_NODES 20000
#define N_EDGES 320000
#define HID 256
#define NR 313          // nodes per partition block (64 blocks x 313 >= 20000)

typedef __attribute__((ext_vector_type(8))) short bf16x8;   // 8 bf16 = 4 VGPRs (MFMA A/B frag)
typedef __attribute__((ext_vector_type(4))) float f32x4;    // MFMA C/D frag

__device__ __forceinline__ float bf2f(ushort u) {
  union { unsigned int i; float f; } v; v.i = ((unsigned int)u) << 16; return v.f;
}
__device__ __forceinline__ ushort f2bf(float f) {
  union { float f; unsigned int i; } v; v.f = f;
  unsigned int r = v.i + 0x7FFFu + ((v.i >> 16) & 1u);   // RNE
  return (ushort)(r >> 16);
}

// ---------------------------------------------------------------------------
// Runtime dtype detection. flags[0]=1 -> x/weights fp32 (else bf16).
// flags[1]=1 -> edges int64 (else int32).
// ---------------------------------------------------------------------------
__global__ void detect_kernel(const void* x1, const void* ei1, int* flags) {
  __shared__ int cnt_wild, cnt_oddnz;
  if (threadIdx.x == 0) { cnt_wild = 0; cnt_oddnz = 0; }
  __syncthreads();
  const ushort* xu = (const ushort*)x1;
  int wild = 0;
#pragma unroll
  for (int k = 0; k < 4; k++) {
    ushort u = xu[threadIdx.x * 4 + k];
    int ex = (u >> 7) & 0xFF;
    if (ex >= 0x90) wild++;
  }
  if (wild) atomicAdd(&cnt_wild, wild);
  const int* ii = (const int*)ei1;
  if (ii[threadIdx.x * 2 + 1] != 0) atomicAdd(&cnt_oddnz, 1);
  __syncthreads();
  if (threadIdx.x == 0) {
    flags[0] = (cnt_wild > 64) ? 1 : 0;
    flags[1] = (cnt_oddnz < 8) ? 1 : 0;
  }
}

// Canonicalize x -> bf16. 4 elems/thread, vectorized both paths.
__global__ void cvt_x_kernel(const void* x0, const void* x1v,
                             ushort* o0, ushort* o1, const int* flags) {
  const void* x = blockIdx.y ? x1v : x0;
  ushort* o = blockIdx.y ? o1 : o0;
  int i4 = (blockIdx.x * 256 + threadIdx.x) * 4;
  if (i4 >= N_NODES * HID) return;
  if (flags[0]) {
    float4 v = *(const float4*)((const float*)x + i4);
    ushort4 w; w.x = f2bf(v.x); w.y = f2bf(v.y); w.z = f2bf(v.z); w.w = f2bf(v.w);
    *(ushort4*)(o + i4) = w;
  } else {
    *(ushort4*)(o + i4) = *(const ushort4*)((const ushort*)x + i4);
  }
}

// Canonicalize all weights/biases -> one packed bf16 buffer.
__global__ void cvt_w_kernel(const void* W1, const void* W2, const void* W3, const void* Wl,
                             const void* b1, const void* b2, const void* b3, const void* bl,
                             ushort* out, const int* flags) {
  int i = blockIdx.x * 256 + threadIdx.x;
  if (i >= 198661) return;
  const void* src; int off;
  if (i < 65536)       { src = W1; off = 0; }
  else if (i < 131072) { src = W2; off = 65536; }
  else if (i < 196608) { src = W3; off = 131072; }
  else if (i < 197888) { src = Wl; off = 196608; }
  else if (i < 198144) { src = b1; off = 197888; }
  else if (i < 198400) { src = b2; off = 198144; }
  else if (i < 198656) { src = b3; off = 198400; }
  else                 { src = bl; off = 198656; }
  int j = i - off;
  out[i] = flags[0] ? f2bf(((const float*)src)[j]) : ((const ushort*)src)[j];
}

// Range-partitioned in-degree histogram: block owns nodes [lo,hi), scans the
// whole dst stream (L2-resident), counts in LDS, writes cnt directly.
// NO device-scope atomics; cnt needs no zero-init.
__global__ __launch_bounds__(1024) void count_part_kernel(
    const void* e0, const void* e1, int* cnt0, int* cnt1, const int* flags) {
  int b = blockIdx.y;
  const void* e = b ? e1 : e0;
  int* cnt = b ? cnt1 : cnt0;
  int lo = blockIdx.x * NR;
  int hi = min(lo + NR, N_NODES);
  int nr = hi - lo;
  __shared__ int h[NR];
  for (int k = threadIdx.x; k < nr; k += 1024) h[k] = 0;
  __syncthreads();
  if (flags[1]) {
    const long long* d = (const long long*)e + N_EDGES;
    for (int i = threadIdx.x * 4; i < N_EDGES; i += 4096) {
      longlong2 p0 = *(const longlong2*)(d + i);
      longlong2 p1 = *(const longlong2*)(d + i + 2);
      int v0 = (int)p0.x, v1 = (int)p0.y, v2 = (int)p1.x, v3 = (int)p1.y;
      if ((unsigned)(v0 - lo) < (unsigned)nr) atomicAdd(&h[v0 - lo], 1);
      if ((unsigned)(v1 - lo) < (unsigned)nr) atomicAdd(&h[v1 - lo], 1);
      if ((unsigned)(v2 - lo) < (unsigned)nr) atomicAdd(&h[v2 - lo], 1);
      if ((unsigned)(v3 - lo) < (unsigned)nr) atomicAdd(&h[v3 - lo], 1);
    }
  } else {
    const int* d = (const int*)e + N_EDGES;
    for (int i = threadIdx.x * 4; i < N_EDGES; i += 4096) {
      int4 v = *(const int4*)(d + i);
      if ((unsigned)(v.x - lo) < (unsigned)nr) atomicAdd(&h[v.x - lo], 1);
      if ((unsigned)(v.y - lo) < (unsigned)nr) atomicAdd(&h[v.y - lo], 1);
      if ((unsigned)(v.z - lo) < (unsigned)nr) atomicAdd(&h[v.z - lo], 1);
      if ((unsigned)(v.w - lo) < (unsigned)nr) atomicAdd(&h[v.w - lo], 1);
    }
  }
  __syncthreads();
  for (int k = threadIdx.x; k < nr; k += 1024) cnt[lo + k] = h[k];
}

__global__ void dinv_kernel(const int* cnt0, const int* cnt1, float* dinv0, float* dinv1) {
  int i = blockIdx.x * blockDim.x + threadIdx.x;
  if (i >= N_NODES) return;
  const int* cnt = blockIdx.y ? cnt1 : cnt0;
  float* dinv = blockIdx.y ? dinv1 : dinv0;
  dinv[i] = rsqrtf((float)cnt[i] + 1.0f);
}

// Exclusive scan -> CSR row_ptr. 1024 threads x 20 counts each.
__global__ __launch_bounds__(1024) void scan_kernel(const int* cnt0, const int* cnt1,
                                                    int* rp0, int* rp1) {
  const int* cnt = blockIdx.x ? cnt1 : cnt0;
  int* rp = blockIdx.x ? rp1 : rp0;
  __shared__ int sd[1024];
  int tid = threadIdx.x;
  int base = tid * 20;
  int pref[20];
  int run = 0;
#pragma unroll
  for (int k = 0; k < 20; k++) {
    int i = base + k;
    run += (i < N_NODES) ? cnt[i] : 0;
    pref[k] = run;
  }
  sd[tid] = run;
  __syncthreads();
  for (int off = 1; off < 1024; off <<= 1) {
    int v = (tid >= off) ? sd[tid - off] : 0;
    __syncthreads();
    sd[tid] += v;
    __syncthreads();
  }
  int offset = sd[tid] - run;
  if (tid == 0) rp[0] = 0;
#pragma unroll
  for (int k = 0; k < 20; k++) {
    int i = base + k;
    if (i < N_NODES) rp[i + 1] = offset + pref[k];
  }
}

// Range-partitioned CSR fill + t accumulation. Block owns [lo,hi); scans all
// edges; dst-in-range -> LDS rank -> slot, writes packed (src,coef) int2;
// src-in-range -> lt[src-lo] += dinv[dst]. No device atomics; t fully written.
__global__ __launch_bounds__(1024) void fill_part_kernel(
    const void* e0, const void* e1,
    const float* dinv0, const float* dinv1,
    const int* rp0, const int* rp1,
    int2* eg0, int2* eg1, float* t0, float* t1, const int* flags) {
  int b = blockIdx.y;
  const void* e = b ? e1 : e0;
  const float* dinv = b ? dinv1 : dinv0;
  const int* rp = b ? rp1 : rp0;
  int2* eg = b ? eg1 : eg0;
  float* t = b ? t1 : t0;
  int lo = blockIdx.x * NR;
  int hi = min(lo + NR, N_NODES);
  int nr = hi - lo;
  __shared__ int lrank[NR];
  __shared__ int lrp[NR];
  __shared__ float ldv[NR];
  __shared__ float lt[NR];
  for (int k = threadIdx.x; k < nr; k += 1024) {
    lrank[k] = 0; lt[k] = 0.f; lrp[k] = rp[lo + k]; ldv[k] = dinv[lo + k];
  }
  __syncthreads();
  bool w64 = flags[1] != 0;
  const int* si32 = (const int*)e;
  const int* di32 = (const int*)e + N_EDGES;
  const long long* si64 = (const long long*)e;
  const long long* di64 = (const long long*)e + N_EDGES;
  for (int i = threadIdx.x * 4; i < N_EDGES; i += 4096) {
    int s[4], d[4];
    if (w64) {
      longlong2 a0 = *(const longlong2*)(si64 + i);
      longlong2 a1 = *(const longlong2*)(si64 + i + 2);
      longlong2 b0 = *(const longlong2*)(di64 + i);
      longlong2 b1 = *(const longlong2*)(di64 + i + 2);
      s[0] = (int)a0.x; s[1] = (int)a0.y; s[2] = (int)a1.x; s[3] = (int)a1.y;
      d[0] = (int)b0.x; d[1] = (int)b0.y; d[2] = (int)b1.x; d[3] = (int)b1.y;
    } else {
      int4 a = *(const int4*)(si32 + i);
      int4 bb = *(const int4*)(di32 + i);
      s[0] = a.x; s[1] = a.y; s[2] = a.z; s[3] = a.w;
      d[0] = bb.x; d[1] = bb.y; d[2] = bb.z; d[3] = bb.w;
    }
#pragma unroll
    for (int k = 0; k < 4; k++) {
      unsigned dd = (unsigned)(d[k] - lo);
      if (dd < (unsigned)nr) {
        int r = atomicAdd(&lrank[dd], 1);
        float cf = dinv[s[k]] * ldv[dd];
        eg[lrp[dd] + r] = make_int2(s[k], __float_as_int(cf));
      }
      unsigned ss = (unsigned)(s[k] - lo);
      if (ss < (unsigned)nr) atomicAdd(&lt[ss], dinv[d[k]]);
    }
  }
  __syncthreads();
  for (int k = threadIdx.x; k < nr; k += 1024) t[lo + k] = lt[k];
}

// C[M,256] = A[M,256] @ W[256,256], bf16 in/out, fp32 MFMA accumulate.
__global__ __launch_bounds__(256) void gemm_kernel(
    const ushort* __restrict__ A0, const ushort* __restrict__ A1,
    const ushort* __restrict__ W,
    ushort* __restrict__ C0, ushort* __restrict__ C1) {
  const ushort* A = blockIdx.z ? A1 : A0;
  ushort* C = blockIdx.z ? C1 : C0;
  int m0 = blockIdx.x * 64;
  int n0 = blockIdx.y * 64;
  __shared__ ushort As[64][40];   // row stride 80 B (multiple of 16, not pow2)
  __shared__ ushort Bs[64][40];   // B^T tile: Bs[n][k] = W[k0+k][n0+n]
  int tid = threadIdx.x;
  int wave = tid >> 6, lane = tid & 63;
  int quad = lane >> 4, r16 = lane & 15;
  f32x4 acc0 = {0.f, 0.f, 0.f, 0.f}, acc1 = acc0, acc2 = acc0, acc3 = acc0;
  int la_row = tid >> 2;
  int la_off = (tid & 3) * 8;
  int lb_k = tid >> 3;
  int lb_n = (tid & 7) * 8;
  for (int k0 = 0; k0 < 256; k0 += 32) {
    int gr = m0 + la_row;
    int4 va = {0, 0, 0, 0};
    if (gr < N_NODES) va = *(const int4*)(A + gr * 256 + k0 + la_off);
    *(int4*)&As[la_row][la_off] = va;
    int4 vb = *(const int4*)(W + (k0 + lb_k) * 256 + n0 + lb_n);
    ushort tmp[8];
    *(int4*)tmp = vb;
#pragma unroll
    for (int j = 0; j < 8; j++) Bs[lb_n + j][lb_k] = tmp[j];
    __syncthreads();
    bf16x8 a  = *(const bf16x8*)&As[wave * 16 + r16][quad * 8];
    bf16x8 b0 = *(const bf16x8*)&Bs[r16][quad * 8];
    bf16x8 b1 = *(const bf16x8*)&Bs[16 + r16][quad * 8];
    bf16x8 b2 = *(const bf16x8*)&Bs[32 + r16][quad * 8];
    bf16x8 b3 = *(const bf16x8*)&Bs[48 + r16][quad * 8];
    acc0 = __builtin_amdgcn_mfma_f32_16x16x32_bf16(a, b0, acc0, 0, 0, 0);
    acc1 = __builtin_amdgcn_mfma_f32_16x16x32_bf16(a, b1, acc1, 0, 0, 0);
    acc2 = __builtin_amdgcn_mfma_f32_16x16x32_bf16(a, b2, acc2, 0, 0, 0);
    acc3 = __builtin_amdgcn_mfma_f32_16x16x32_bf16(a, b3, acc3, 0, 0, 0);
    __syncthreads();
  }
  int orow = m0 + wave * 16 + quad * 4;
#pragma unroll
  for (int r = 0; r < 4; r++) {
    int gr = orow + r;
    if (gr < N_NODES) {
      ushort* cp = C + gr * 256 + n0 + r16;
      cp[0]  = f2bf(acc0[r]);
      cp[16] = f2bf(acc1[r]);
      cp[32] = f2bf(acc2[r]);
      cp[48] = f2bf(acc3[r]);
    }
  }
}

// H[i] = relu( dinv_i^2 * XW[i] + sum_e coef_e * XW[col_e] + bias ).
// 4 waves/block = 4 nodes; lane owns 4 features; edges packed (src,coef) int2;
// x4 unroll -> 4 row-gathers in flight.
__global__ __launch_bounds__(256) void agg_kernel(
    const ushort* __restrict__ XW0, const ushort* __restrict__ XW1,
    const float* __restrict__ dinv0, const float* __restrict__ dinv1,
    const int* __restrict__ rp0, const int* __restrict__ rp1,
    const int2* __restrict__ eg0, const int2* __restrict__ eg1,
    const ushort* __restrict__ bias,
    ushort* __restrict__ H0, ushort* __restrict__ H1) {
  int b = blockIdx.y;
  const ushort* XW = b ? XW1 : XW0;
  const float* dinv = b ? dinv1 : dinv0;
  const int* rp = b ? rp1 : rp0;
  const int2* eg = b ? eg1 : eg0;
  ushort* H = b ? H1 : H0;
  int wave = threadIdx.x >> 6, lane = threadIdx.x & 63;
  int i = blockIdx.x * 4 + wave;          // 20000 = 5000*4 exact
  int f4 = lane * 4;
  float di = dinv[i];
  float self = di * di;
  ushort4 v = *(const ushort4*)(XW + i * 256 + f4);
  float a0 = self * bf2f(v.x), a1 = self * bf2f(v.y);
  float a2 = self * bf2f(v.z), a3 = self * bf2f(v.w);
  float c0_ = 0.f, c1_ = 0.f, c2_ = 0.f, c3_ = 0.f;
  int e0 = rp[i], e1 = rp[i + 1];
  int e = e0;
  for (; e + 3 < e1; e += 4) {
    int2 p0 = eg[e], p1 = eg[e + 1], p2 = eg[e + 2], p3 = eg[e + 3];
    ushort4 u0 = *(const ushort4*)(XW + p0.x * 256 + f4);
    ushort4 u1 = *(const ushort4*)(XW + p1.x * 256 + f4);
    ushort4 u2 = *(const ushort4*)(XW + p2.x * 256 + f4);
    ushort4 u3 = *(const ushort4*)(XW + p3.x * 256 + f4);
    float w0 = __int_as_float(p0.y), w1 = __int_as_float(p1.y);
    float w2 = __int_as_float(p2.y), w3 = __int_as_float(p3.y);
    a0 += w0 * bf2f(u0.x); a1 += w0 * bf2f(u0.y); a2 += w0 * bf2f(u0.z); a3 += w0 * bf2f(u0.w);
    c0_ += w1 * bf2f(u1.x); c1_ += w1 * bf2f(u1.y); c2_ += w1 * bf2f(u1.z); c3_ += w1 * bf2f(u1.w);
    a0 += w2 * bf2f(u2.x); a1 += w2 * bf2f(u2.y); a2 += w2 * bf2f(u2.z); a3 += w2 * bf2f(u2.w);
    c0_ += w3 * bf2f(u3.x); c1_ += w3 * bf2f(u3.y); c2_ += w3 * bf2f(u3.z); c3_ += w3 * bf2f(u3.w);
  }
  for (; e < e1; e++) {
    int2 pp = eg[e];
    float c = __int_as_float(pp.y);
    ushort4 u = *(const ushort4*)(XW + pp.x * 256 + f4);
    a0 += c * bf2f(u.x); a1 += c * bf2f(u.y); a2 += c * bf2f(u.z); a3 += c * bf2f(u.w);
  }
  a0 += c0_; a1 += c1_; a2 += c2_; a3 += c3_;
  ushort4 bb = *(const ushort4*)(bias + f4);
  a0 = fmaxf(a0 + bf2f(bb.x), 0.f);
  a1 = fmaxf(a1 + bf2f(bb.y), 0.f);
  a2 = fmaxf(a2 + bf2f(bb.z), 0.f);
  a3 = fmaxf(a3 + bf2f(bb.w), 0.f);
  ushort4 o; o.x = f2bf(a0); o.y = f2bf(a1); o.z = f2bf(a2); o.w = f2bf(a3);
  *(ushort4*)(H + i * 256 + f4) = o;
}

// Partial column sums: wave w of block handles rows j = (blk*4+w) + 256*k,
// lane reads ushort4 (4 features). Block partial -> P[(branch*64+blk)*256+f].
__global__ __launch_bounds__(256) void colsum_kernel(
    const ushort* __restrict__ H0, const ushort* __restrict__ H1,
    const float* __restrict__ dinv0, const float* __restrict__ dinv1,
    const float* __restrict__ t0, const float* __restrict__ t1,
    float* __restrict__ P) {
  int b = blockIdx.y;
  const ushort* H = b ? H1 : H0;
  const float* dinv = b ? dinv1 : dinv0;
  const float* t = b ? t1 : t0;
  int wave = threadIdx.x >> 6, lane = threadIdx.x & 63;
  int wid = blockIdx.x * 4 + wave;        // 0..255
  int f4 = lane * 4;
  float a0 = 0.f, a1 = 0.f, a2 = 0.f, a3 = 0.f;
  for (int j = wid; j < N_NODES; j += 256) {
    float dj = dinv[j];
    float c = dj * (t[j] + dj);
    ushort4 u = *(const ushort4*)(H + j * 256 + f4);
    a0 += c * bf2f(u.x); a1 += c * bf2f(u.y);
    a2 += c * bf2f(u.z); a3 += c * bf2f(u.w);
  }
  __shared__ float part[4][256];
  part[wave][f4 + 0] = a0; part[wave][f4 + 1] = a1;
  part[wave][f4 + 2] = a2; part[wave][f4 + 3] = a3;
  __syncthreads();
  int f = threadIdx.x;
  float ssum = part[0][f] + part[1][f] + part[2][f] + part[3][f];
  P[(b * 64 + blockIdx.x) * 256 + f] = ssum;
}

// s = reduce partials; pooled = ((s0+s1)@W3)/(2N)+b3 ; out = pooled@Wl + bl
__global__ __launch_bounds__(256) void final_kernel(
    const float* __restrict__ P,
    const ushort* __restrict__ W3, const ushort* __restrict__ b3,
    const ushort* __restrict__ Wl, const ushort* __restrict__ bl,
    void* __restrict__ out, const int* __restrict__ flags) {
  __shared__ float v[256];
  __shared__ float pooled[256];
  int t = threadIdx.x;
  float acc0 = 0.f, acc1 = 0.f;
  for (int b = 0; b < 64; b++) {
    acc0 += P[b * 256 + t];
    acc1 += P[(64 + b) * 256 + t];
  }
  v[t] = acc0 + acc1;
  __syncthreads();
  float acc = 0.f;
  for (int f = 0; f < 256; f++) acc += v[f] * bf2f(W3[f * 256 + t]);
  pooled[t] = acc * (1.0f / (2.0f * N_NODES)) + bf2f(b3[t]);
  __syncthreads();
  if (t < 5) {
    float o = bf2f(bl[t]);
    for (int h = 0; h < 256; h++) o += pooled[h] * bf2f(Wl[h * 5 + t]);
    if (flags[0]) ((float*)out)[t] = o;
    else ((ushort*)out)[t] = f2bf(o);
  }
}

extern "C" void kernel_launch(void* const* d_in, const int* in_sizes, int n_in,
                              void* d_out, int out_size, void* d_ws, size_t ws_size,
                              hipStream_t stream) {
  const void* x1 = d_in[0];
  const void* ei1 = d_in[1];
  const void* x2 = d_in[2];
  const void* ei2 = d_in[3];
  const void* W1 = d_in[4];
  const void* b1 = d_in[5];
  const void* W2 = d_in[6];
  const void* b2 = d_in[7];
  const void* W3 = d_in[8];
  const void* b3 = d_in[9];
  const void* Wl = d_in[10];
  const void* bl = d_in[11];

  char* p = (char*)d_ws;
  auto alloc = [&](size_t bytes) {
    char* r = p;
    p += (bytes + 255) & ~size_t(255);
    return r;
  };
  int* flags   = (int*)alloc(256);
  float* dinv0 = (float*)alloc(N_NODES * 4);
  float* dinv1 = (float*)alloc(N_NODES * 4);
  float* t0    = (float*)alloc(N_NODES * 4);
  float* t1    = (float*)alloc(N_NODES * 4);
  int* cnt0    = (int*)alloc(N_NODES * 4);
  int* cnt1    = (int*)alloc(N_NODES * 4);
  int* rp0     = (int*)alloc((N_NODES + 1) * 4);
  int* rp1     = (int*)alloc((N_NODES + 1) * 4);
  int2* eg0    = (int2*)alloc((size_t)N_EDGES * 8);
  int2* eg1    = (int2*)alloc((size_t)N_EDGES * 8);
  float* Pp    = (float*)alloc(2 * 64 * 256 * 4);
  ushort* wbuf = (ushort*)alloc(198661 * 2);
  ushort* xw0  = (ushort*)alloc((size_t)N_NODES * HID * 2);
  ushort* xw1  = (ushort*)alloc((size_t)N_NODES * HID * 2);
  ushort* xc0  = (ushort*)alloc((size_t)N_NODES * HID * 2);
  ushort* xc1  = (ushort*)alloc((size_t)N_NODES * HID * 2);
  // xc dead after gemm1 reads it; h first written by agg1 (after gemm1).
  ushort* h0 = xc0;
  ushort* h1 = xc1;

  ushort* Wc1 = wbuf + 0;
  ushort* Wc2 = wbuf + 65536;
  ushort* Wc3 = wbuf + 131072;
  ushort* Wlc = wbuf + 196608;
  ushort* bc1 = wbuf + 197888;
  ushort* bc2 = wbuf + 198144;
  ushort* bc3 = wbuf + 198400;
  ushort* blc = wbuf + 198656;

  // --- dtype detection + canonicalization + graph prep (no device atomics) ---
  detect_kernel<<<1, 256, 0, stream>>>(x1, ei1, flags);
  cvt_x_kernel<<<dim3(N_NODES * HID / 1024, 2), 256, 0, stream>>>(
      x1, x2, xc0, xc1, flags);
  cvt_w_kernel<<<(198661 + 255) / 256, 256, 0, stream>>>(
      W1, W2, W3, Wl, b1, b2, b3, bl, wbuf, flags);
  count_part_kernel<<<dim3(64, 2), 1024, 0, stream>>>(ei1, ei2, cnt0, cnt1, flags);
  dinv_kernel<<<dim3((N_NODES + 255) / 256, 2), 256, 0, stream>>>(cnt0, cnt1, dinv0, dinv1);
  scan_kernel<<<2, 1024, 0, stream>>>(cnt0, cnt1, rp0, rp1);
  fill_part_kernel<<<dim3(64, 2), 1024, 0, stream>>>(
      ei1, ei2, dinv0, dinv1, rp0, rp1, eg0, eg1, t0, t1, flags);

  // Layer 1: xw = x @ W1 ; h = relu(agg(xw) + b1)
  gemm_kernel<<<dim3(313, 4, 2), 256, 0, stream>>>(xc0, xc1, Wc1, xw0, xw1);
  agg_kernel<<<dim3(N_NODES / 4, 2), 256, 0, stream>>>(
      xw0, xw1, dinv0, dinv1, rp0, rp1, eg0, eg1, bc1, h0, h1);

  // Layer 2: xw = h @ W2 ; h = relu(agg(xw) + b2)
  gemm_kernel<<<dim3(313, 4, 2), 256, 0, stream>>>(h0, h1, Wc2, xw0, xw1);
  agg_kernel<<<dim3(N_NODES / 4, 2), 256, 0, stream>>>(
      xw0, xw1, dinv0, dinv1, rp0, rp1, eg0, eg1, bc2, h0, h1);

  // Layer 3 + pool collapsed: s = sum_j c_j h2_j ; out = ((s0+s1)W3/(2N)+b3)@Wl+bl
  colsum_kernel<<<dim3(64, 2), 256, 0, stream>>>(h0, h1, dinv0, dinv1, t0, t1, Pp);
  final_kernel<<<1, 256, 0, stream>>>(Pp, Wc3, bc3, Wlc, blc, d_out, flags);
}

// Round 5
// 414.543 us; speedup vs baseline: 1.1579x; 1.1579x over previous
//
#include <hip/hip_runtime.h>
#include <hip/hip_bf16.h>

#define N_NODES 20000
#define N_EDGES 320000
#define HID 256

typedef __attribute__((ext_vector_type(8))) short bf16x8;   // 8 bf16 = 4 VGPRs (MFMA A/B frag)
typedef __attribute__((ext_vector_type(4))) float f32x4;    // MFMA C/D frag

__device__ __forceinline__ float bf2f(ushort u) {
  union { unsigned int i; float f; } v; v.i = ((unsigned int)u) << 16; return v.f;
}
__device__ __forceinline__ ushort f2bf(float f) {
  union { float f; unsigned int i; } v; v.f = f;
  unsigned int r = v.i + 0x7FFFu + ((v.i >> 16) & 1u);   // RNE
  return (ushort)(r >> 16);
}

// ---------------------------------------------------------------------------
// Runtime dtype detection. flags[0]=1 -> x/weights fp32 (else bf16).
// flags[1]=1 -> edges int64 (else int32).
// ---------------------------------------------------------------------------
__global__ void detect_kernel(const void* x1, const void* ei1, int* flags) {
  __shared__ int cnt_wild, cnt_oddnz;
  if (threadIdx.x == 0) { cnt_wild = 0; cnt_oddnz = 0; }
  __syncthreads();
  const ushort* xu = (const ushort*)x1;
  int wild = 0;
#pragma unroll
  for (int k = 0; k < 4; k++) {
    ushort u = xu[threadIdx.x * 4 + k];
    int ex = (u >> 7) & 0xFF;
    if (ex >= 0x90) wild++;
  }
  if (wild) atomicAdd(&cnt_wild, wild);
  const int* ii = (const int*)ei1;
  if (ii[threadIdx.x * 2 + 1] != 0) atomicAdd(&cnt_oddnz, 1);
  __syncthreads();
  if (threadIdx.x == 0) {
    flags[0] = (cnt_wild > 64) ? 1 : 0;
    flags[1] = (cnt_oddnz < 8) ? 1 : 0;
  }
}

// Zero accumulated state (ws is poisoned 0xAA before every timed call).
__global__ void init_kernel(int* cnt0, int* cnt1, float* t0, float* t1) {
  int i = blockIdx.x * blockDim.x + threadIdx.x;
  if (i < N_NODES) { cnt0[i] = 0; cnt1[i] = 0; t0[i] = 0.f; t1[i] = 0.f; }
}

// Canonicalize edge_index -> int32 AND fused dst-histogram with rank capture:
// the atomicAdd return value IS the edge's rank within its dst bucket
// (measured r2/r3: 640K device atomics ~= 36-40 us; cheaper than any
// replication scheme -- r4's partitioned variant was 3x slower).
__global__ void cvt_ei_count_kernel(const void* e0, const void* e1,
                                    int* o0, int* o1,
                                    int* cnt0, int* cnt1,
                                    int* rank0, int* rank1, const int* flags) {
  int b = blockIdx.y;
  const void* e = b ? e1 : e0;
  int* o = b ? o1 : o0;
  int* cnt = b ? cnt1 : cnt0;
  int* rank = b ? rank1 : rank0;
  int i = blockIdx.x * 256 + threadIdx.x;
  if (i >= 2 * N_EDGES) return;
  int v = flags[1] ? (int)((const long long*)e)[i] : ((const int*)e)[i];
  o[i] = v;
  if (i >= N_EDGES) rank[i - N_EDGES] = atomicAdd(&cnt[v], 1);
}

// Canonicalize x -> bf16. 4 elems/thread, vectorized both paths.
__global__ void cvt_x_kernel(const void* x0, const void* x1v,
                             ushort* o0, ushort* o1, const int* flags) {
  const void* x = blockIdx.y ? x1v : x0;
  ushort* o = blockIdx.y ? o1 : o0;
  int i4 = (blockIdx.x * 256 + threadIdx.x) * 4;
  if (i4 >= N_NODES * HID) return;
  if (flags[0]) {
    float4 v = *(const float4*)((const float*)x + i4);
    ushort4 w; w.x = f2bf(v.x); w.y = f2bf(v.y); w.z = f2bf(v.z); w.w = f2bf(v.w);
    *(ushort4*)(o + i4) = w;
  } else {
    *(ushort4*)(o + i4) = *(const ushort4*)((const ushort*)x + i4);
  }
}

// Canonicalize all weights/biases -> one packed bf16 buffer.
// Layout: W1[0] W2[65536] W3[131072] Wl[196608] b1[197888] b2[198144]
//         b3[198400] bl[198656]; total 198661 elems.
__global__ void cvt_w_kernel(const void* W1, const void* W2, const void* W3, const void* Wl,
                             const void* b1, const void* b2, const void* b3, const void* bl,
                             ushort* out, const int* flags) {
  int i = blockIdx.x * 256 + threadIdx.x;
  if (i >= 198661) return;
  const void* src; int off;
  if (i < 65536)       { src = W1; off = 0; }
  else if (i < 131072) { src = W2; off = 65536; }
  else if (i < 196608) { src = W3; off = 131072; }
  else if (i < 197888) { src = Wl; off = 196608; }
  else if (i < 198144) { src = b1; off = 197888; }
  else if (i < 198400) { src = b2; off = 198144; }
  else if (i < 198656) { src = b3; off = 198400; }
  else                 { src = bl; off = 198656; }
  int j = i - off;
  out[i] = flags[0] ? f2bf(((const float*)src)[j]) : ((const ushort*)src)[j];
}

// Exclusive scan -> CSR row_ptr, fused with dinv = rsqrt(cnt+1) (cnt is
// already being loaded here). 1024 threads x 20 counts each, one 10-step
// LDS scan of per-thread totals.
__global__ __launch_bounds__(1024) void scan_kernel(const int* cnt0, const int* cnt1,
                                                    int* rp0, int* rp1,
                                                    float* dinv0, float* dinv1) {
  const int* cnt = blockIdx.x ? cnt1 : cnt0;
  int* rp = blockIdx.x ? rp1 : rp0;
  float* dinv = blockIdx.x ? dinv1 : dinv0;
  __shared__ int sd[1024];
  int tid = threadIdx.x;
  int base = tid * 20;
  int pref[20];
  int run = 0;
#pragma unroll
  for (int k = 0; k < 20; k++) {
    int i = base + k;
    int c = (i < N_NODES) ? cnt[i] : 0;
    if (i < N_NODES) dinv[i] = rsqrtf((float)c + 1.0f);
    run += c;
    pref[k] = run;
  }
  sd[tid] = run;
  __syncthreads();
  for (int off = 1; off < 1024; off <<= 1) {
    int v = (tid >= off) ? sd[tid - off] : 0;
    __syncthreads();
    sd[tid] += v;
    __syncthreads();
  }
  int offset = sd[tid] - run;
  if (tid == 0) rp[0] = 0;
#pragma unroll
  for (int k = 0; k < 20; k++) {
    int i = base + k;
    if (i < N_NODES) rp[i + 1] = offset + pref[k];
  }
}

// Fill CSR (packed (src,coef) int2) using precomputed rank (no slot atomic),
// plus t[src] += dinv[dst] (feeds layer-3 shortcut c_j = dinv_j*(t_j+dinv_j)).
__global__ void fill_kernel(const int* ei0, const int* ei1,
                            const float* dinv0, const float* dinv1,
                            const int* rp0, const int* rp1,
                            const int* rank0, const int* rank1,
                            int2* eg0, int2* eg1,
                            float* t0, float* t1) {
  int e = blockIdx.x * blockDim.x + threadIdx.x;
  if (e >= N_EDGES) return;
  int b = blockIdx.y;
  const int* ei = b ? ei1 : ei0;
  const float* dinv = b ? dinv1 : dinv0;
  const int* rp = b ? rp1 : rp0;
  const int* rank = b ? rank1 : rank0;
  int2* eg = b ? eg1 : eg0;
  float* t = b ? t1 : t0;
  int src = ei[e], dst = ei[N_EDGES + e];
  int slot = rp[dst] + rank[e];
  float dd = dinv[dst];
  eg[slot] = make_int2(src, __float_as_int(dinv[src] * dd));
  atomicAdd(&t[src], dd);
}

// C[M,256] = A[M,256] @ W[256,256], bf16 in/out, fp32 MFMA accumulate.
// Block 256 thr = 4 waves; 64x64 tile; BK=32; 16x16x32 bf16 MFMA.
__global__ __launch_bounds__(256) void gemm_kernel(
    const ushort* __restrict__ A0, const ushort* __restrict__ A1,
    const ushort* __restrict__ W,
    ushort* __restrict__ C0, ushort* __restrict__ C1) {
  const ushort* A = blockIdx.z ? A1 : A0;
  ushort* C = blockIdx.z ? C1 : C0;
  int m0 = blockIdx.x * 64;
  int n0 = blockIdx.y * 64;
  __shared__ ushort As[64][40];   // row stride 80 B (multiple of 16, not pow2)
  __shared__ ushort Bs[64][40];   // B^T tile: Bs[n][k] = W[k0+k][n0+n]
  int tid = threadIdx.x;
  int wave = tid >> 6, lane = tid & 63;
  int quad = lane >> 4, r16 = lane & 15;
  f32x4 acc0 = {0.f, 0.f, 0.f, 0.f}, acc1 = acc0, acc2 = acc0, acc3 = acc0;
  int la_row = tid >> 2;
  int la_off = (tid & 3) * 8;
  int lb_k = tid >> 3;
  int lb_n = (tid & 7) * 8;
  for (int k0 = 0; k0 < 256; k0 += 32) {
    int gr = m0 + la_row;
    int4 va = {0, 0, 0, 0};
    if (gr < N_NODES) va = *(const int4*)(A + gr * 256 + k0 + la_off);
    *(int4*)&As[la_row][la_off] = va;
    int4 vb = *(const int4*)(W + (k0 + lb_k) * 256 + n0 + lb_n);
    ushort tmp[8];
    *(int4*)tmp = vb;
#pragma unroll
    for (int j = 0; j < 8; j++) Bs[lb_n + j][lb_k] = tmp[j];
    __syncthreads();
    bf16x8 a  = *(const bf16x8*)&As[wave * 16 + r16][quad * 8];
    bf16x8 b0 = *(const bf16x8*)&Bs[r16][quad * 8];
    bf16x8 b1 = *(const bf16x8*)&Bs[16 + r16][quad * 8];
    bf16x8 b2 = *(const bf16x8*)&Bs[32 + r16][quad * 8];
    bf16x8 b3 = *(const bf16x8*)&Bs[48 + r16][quad * 8];
    acc0 = __builtin_amdgcn_mfma_f32_16x16x32_bf16(a, b0, acc0, 0, 0, 0);
    acc1 = __builtin_amdgcn_mfma_f32_16x16x32_bf16(a, b1, acc1, 0, 0, 0);
    acc2 = __builtin_amdgcn_mfma_f32_16x16x32_bf16(a, b2, acc2, 0, 0, 0);
    acc3 = __builtin_amdgcn_mfma_f32_16x16x32_bf16(a, b3, acc3, 0, 0, 0);
    __syncthreads();
  }
  int orow = m0 + wave * 16 + quad * 4;
#pragma unroll
  for (int r = 0; r < 4; r++) {
    int gr = orow + r;
    if (gr < N_NODES) {
      ushort* cp = C + gr * 256 + n0 + r16;
      cp[0]  = f2bf(acc0[r]);
      cp[16] = f2bf(acc1[r]);
      cp[32] = f2bf(acc2[r]);
      cp[48] = f2bf(acc3[r]);
    }
  }
}

// H[i] = relu( dinv_i^2 * XW[i] + sum_e coef_e * XW[col_e] + bias ).
// 4 waves/block = 4 nodes; lane owns 4 features; edges packed (src,coef) int2;
// x4 unroll with dual accumulators -> 4 row-gathers in flight.
__global__ __launch_bounds__(256) void agg_kernel(
    const ushort* __restrict__ XW0, const ushort* __restrict__ XW1,
    const float* __restrict__ dinv0, const float* __restrict__ dinv1,
    const int* __restrict__ rp0, const int* __restrict__ rp1,
    const int2* __restrict__ eg0, const int2* __restrict__ eg1,
    const ushort* __restrict__ bias,
    ushort* __restrict__ H0, ushort* __restrict__ H1) {
  int b = blockIdx.y;
  const ushort* XW = b ? XW1 : XW0;
  const float* dinv = b ? dinv1 : dinv0;
  const int* rp = b ? rp1 : rp0;
  const int2* eg = b ? eg1 : eg0;
  ushort* H = b ? H1 : H0;
  int wave = threadIdx.x >> 6, lane = threadIdx.x & 63;
  int i = blockIdx.x * 4 + wave;          // 20000 = 5000*4 exact
  int f4 = lane * 4;
  float di = dinv[i];
  float self = di * di;
  ushort4 v = *(const ushort4*)(XW + i * 256 + f4);
  float a0 = self * bf2f(v.x), a1 = self * bf2f(v.y);
  float a2 = self * bf2f(v.z), a3 = self * bf2f(v.w);
  float c0_ = 0.f, c1_ = 0.f, c2_ = 0.f, c3_ = 0.f;
  int e0 = rp[i], e1 = rp[i + 1];
  int e = e0;
  for (; e + 3 < e1; e += 4) {
    int2 p0 = eg[e], p1 = eg[e + 1], p2 = eg[e + 2], p3 = eg[e + 3];
    ushort4 u0 = *(const ushort4*)(XW + p0.x * 256 + f4);
    ushort4 u1 = *(const ushort4*)(XW + p1.x * 256 + f4);
    ushort4 u2 = *(const ushort4*)(XW + p2.x * 256 + f4);
    ushort4 u3 = *(const ushort4*)(XW + p3.x * 256 + f4);
    float w0 = __int_as_float(p0.y), w1 = __int_as_float(p1.y);
    float w2 = __int_as_float(p2.y), w3 = __int_as_float(p3.y);
    a0 += w0 * bf2f(u0.x); a1 += w0 * bf2f(u0.y); a2 += w0 * bf2f(u0.z); a3 += w0 * bf2f(u0.w);
    c0_ += w1 * bf2f(u1.x); c1_ += w1 * bf2f(u1.y); c2_ += w1 * bf2f(u1.z); c3_ += w1 * bf2f(u1.w);
    a0 += w2 * bf2f(u2.x); a1 += w2 * bf2f(u2.y); a2 += w2 * bf2f(u2.z); a3 += w2 * bf2f(u2.w);
    c0_ += w3 * bf2f(u3.x); c1_ += w3 * bf2f(u3.y); c2_ += w3 * bf2f(u3.z); c3_ += w3 * bf2f(u3.w);
  }
  for (; e < e1; e++) {
    int2 pp = eg[e];
    float c = __int_as_float(pp.y);
    ushort4 u = *(const ushort4*)(XW + pp.x * 256 + f4);
    a0 += c * bf2f(u.x); a1 += c * bf2f(u.y); a2 += c * bf2f(u.z); a3 += c * bf2f(u.w);
  }
  a0 += c0_; a1 += c1_; a2 += c2_; a3 += c3_;
  ushort4 bb = *(const ushort4*)(bias + f4);
  a0 = fmaxf(a0 + bf2f(bb.x), 0.f);
  a1 = fmaxf(a1 + bf2f(bb.y), 0.f);
  a2 = fmaxf(a2 + bf2f(bb.z), 0.f);
  a3 = fmaxf(a3 + bf2f(bb.w), 0.f);
  ushort4 o; o.x = f2bf(a0); o.y = f2bf(a1); o.z = f2bf(a2); o.w = f2bf(a3);
  *(ushort4*)(H + i * 256 + f4) = o;
}

// Partial column sums: wave w of block handles rows j = (blk*4+w) + 256*k,
// lane reads ushort4 (4 features). Block partial -> P[(branch*64+blk)*256+f].
__global__ __launch_bounds__(256) void colsum_kernel(
    const ushort* __restrict__ H0, const ushort* __restrict__ H1,
    const float* __restrict__ dinv0, const float* __restrict__ dinv1,
    const float* __restrict__ t0, const float* __restrict__ t1,
    float* __restrict__ P) {
  int b = blockIdx.y;
  const ushort* H = b ? H1 : H0;
  const float* dinv = b ? dinv1 : dinv0;
  const float* t = b ? t1 : t0;
  int wave = threadIdx.x >> 6, lane = threadIdx.x & 63;
  int wid = blockIdx.x * 4 + wave;        // 0..255
  int f4 = lane * 4;
  float a0 = 0.f, a1 = 0.f, a2 = 0.f, a3 = 0.f;
  for (int j = wid; j < N_NODES; j += 256) {
    float dj = dinv[j];
    float c = dj * (t[j] + dj);
    ushort4 u = *(const ushort4*)(H + j * 256 + f4);
    a0 += c * bf2f(u.x); a1 += c * bf2f(u.y);
    a2 += c * bf2f(u.z); a3 += c * bf2f(u.w);
  }
  __shared__ float part[4][256];
  part[wave][f4 + 0] = a0; part[wave][f4 + 1] = a1;
  part[wave][f4 + 2] = a2; part[wave][f4 + 3] = a3;
  __syncthreads();
  int f = threadIdx.x;
  float ssum = part[0][f] + part[1][f] + part[2][f] + part[3][f];
  P[(b * 64 + blockIdx.x) * 256 + f] = ssum;
}

// s = reduce partials; pooled = ((s0+s1)@W3)/(2N)+b3 ; out = pooled@Wl + bl
__global__ __launch_bounds__(256) void final_kernel(
    const float* __restrict__ P,
    const ushort* __restrict__ W3, const ushort* __restrict__ b3,
    const ushort* __restrict__ Wl, const ushort* __restrict__ bl,
    void* __restrict__ out, const int* __restrict__ flags) {
  __shared__ float v[256];
  __shared__ float pooled[256];
  int t = threadIdx.x;
  float acc0 = 0.f, acc1 = 0.f;
  for (int b = 0; b < 64; b++) {
    acc0 += P[b * 256 + t];
    acc1 += P[(64 + b) * 256 + t];
  }
  v[t] = acc0 + acc1;
  __syncthreads();
  float acc = 0.f;
  for (int f = 0; f < 256; f++) acc += v[f] * bf2f(W3[f * 256 + t]);
  pooled[t] = acc * (1.0f / (2.0f * N_NODES)) + bf2f(b3[t]);
  __syncthreads();
  if (t < 5) {
    float o = bf2f(bl[t]);
    for (int h = 0; h < 256; h++) o += pooled[h] * bf2f(Wl[h * 5 + t]);
    if (flags[0]) ((float*)out)[t] = o;
    else ((ushort*)out)[t] = f2bf(o);
  }
}

extern "C" void kernel_launch(void* const* d_in, const int* in_sizes, int n_in,
                              void* d_out, int out_size, void* d_ws, size_t ws_size,
                              hipStream_t stream) {
  const void* x1 = d_in[0];
  const void* ei1 = d_in[1];
  const void* x2 = d_in[2];
  const void* ei2 = d_in[3];
  const void* W1 = d_in[4];
  const void* b1 = d_in[5];
  const void* W2 = d_in[6];
  const void* b2 = d_in[7];
  const void* W3 = d_in[8];
  const void* b3 = d_in[9];
  const void* Wl = d_in[10];
  const void* bl = d_in[11];

  char* p = (char*)d_ws;
  auto alloc = [&](size_t bytes) {
    char* r = p;
    p += (bytes + 255) & ~size_t(255);
    return r;
  };
  int* flags   = (int*)alloc(256);
  float* dinv0 = (float*)alloc(N_NODES * 4);
  float* dinv1 = (float*)alloc(N_NODES * 4);
  float* t0    = (float*)alloc(N_NODES * 4);
  float* t1    = (float*)alloc(N_NODES * 4);
  int* cnt0    = (int*)alloc(N_NODES * 4);
  int* cnt1    = (int*)alloc(N_NODES * 4);
  int* rp0     = (int*)alloc((N_NODES + 1) * 4);
  int* rp1     = (int*)alloc((N_NODES + 1) * 4);
  int2* eg0    = (int2*)alloc((size_t)N_EDGES * 8);
  int2* eg1    = (int2*)alloc((size_t)N_EDGES * 8);
  float* Pp    = (float*)alloc(2 * 64 * 256 * 4);
  ushort* wbuf = (ushort*)alloc(198661 * 2);
  ushort* xw0  = (ushort*)alloc((size_t)N_NODES * HID * 2);
  ushort* xw1  = (ushort*)alloc((size_t)N_NODES * HID * 2);
  ushort* xc0  = (ushort*)alloc((size_t)N_NODES * HID * 2);
  ushort* xc1  = (ushort*)alloc((size_t)N_NODES * HID * 2);
  // Lifetime aliasing: ei32+rank live only until fill_kernel; xw0 is first
  // written by gemm1 (after fill). 2*2.56 + 2*1.28 = 7.7MB <= 10.24MB.
  int* ei32_0 = (int*)xw0;
  int* ei32_1 = ei32_0 + 2 * N_EDGES;
  int* rank0  = ei32_1 + 2 * N_EDGES;
  int* rank1  = rank0 + N_EDGES;
  // xc dead after gemm1 reads it; h first written by agg1 (after gemm1).
  ushort* h0 = xc0;
  ushort* h1 = xc1;

  ushort* Wc1 = wbuf + 0;
  ushort* Wc2 = wbuf + 65536;
  ushort* Wc3 = wbuf + 131072;
  ushort* Wlc = wbuf + 196608;
  ushort* bc1 = wbuf + 197888;
  ushort* bc2 = wbuf + 198144;
  ushort* bc3 = wbuf + 198400;
  ushort* blc = wbuf + 198656;

  // --- dtype detection + canonicalization + graph prep ---
  detect_kernel<<<1, 256, 0, stream>>>(x1, ei1, flags);
  init_kernel<<<(N_NODES + 255) / 256, 256, 0, stream>>>(cnt0, cnt1, t0, t1);
  cvt_ei_count_kernel<<<dim3((2 * N_EDGES + 255) / 256, 2), 256, 0, stream>>>(
      ei1, ei2, ei32_0, ei32_1, cnt0, cnt1, rank0, rank1, flags);
  cvt_x_kernel<<<dim3(N_NODES * HID / 1024, 2), 256, 0, stream>>>(
      x1, x2, xc0, xc1, flags);
  cvt_w_kernel<<<(198661 + 255) / 256, 256, 0, stream>>>(
      W1, W2, W3, Wl, b1, b2, b3, bl, wbuf, flags);
  scan_kernel<<<2, 1024, 0, stream>>>(cnt0, cnt1, rp0, rp1, dinv0, dinv1);
  fill_kernel<<<dim3((N_EDGES + 255) / 256, 2), 256, 0, stream>>>(
      ei32_0, ei32_1, dinv0, dinv1, rp0, rp1, rank0, rank1, eg0, eg1, t0, t1);

  // Layer 1: xw = x @ W1 ; h = relu(agg(xw) + b1)
  gemm_kernel<<<dim3(313, 4, 2), 256, 0, stream>>>(xc0, xc1, Wc1, xw0, xw1);
  agg_kernel<<<dim3(N_NODES / 4, 2), 256, 0, stream>>>(
      xw0, xw1, dinv0, dinv1, rp0, rp1, eg0, eg1, bc1, h0, h1);

  // Layer 2: xw = h @ W2 ; h = relu(agg(xw) + b2)
  gemm_kernel<<<dim3(313, 4, 2), 256, 0, stream>>>(h0, h1, Wc2, xw0, xw1);
  agg_kernel<<<dim3(N_NODES / 4, 2), 256, 0, stream>>>(
      xw0, xw1, dinv0, dinv1, rp0, rp1, eg0, eg1, bc2, h0, h1);

  // Layer 3 + pool collapsed: s = sum_j c_j h2_j ; out = ((s0+s1)W3/(2N)+b3)@Wl+bl
  colsum_kernel<<<dim3(64, 2), 256, 0, stream>>>(h0, h1, dinv0, dinv1, t0, t1, Pp);
  final_kernel<<<1, 256, 0, stream>>>(Pp, Wc3, bc3, Wlc, blc, d_out, flags);
}

// Round 6
// 381.404 us; speedup vs baseline: 1.2585x; 1.0869x over previous
//
#include <hip/hip_runtime.h>
#include <hip/hip_bf16.h>

#define N_NODES 20000
#define N_EDGES 320000
#define HID 256

typedef __attribute__((ext_vector_type(8))) short bf16x8;   // 8 bf16 = 4 VGPRs (MFMA A/B frag)
typedef __attribute__((ext_vector_type(4))) float f32x4;    // MFMA C/D frag
typedef __attribute__((ext_vector_type(8))) unsigned short us8;  // 16B row chunk

__device__ __forceinline__ float bf2f(ushort u) {
  union { unsigned int i; float f; } v; v.i = ((unsigned int)u) << 16; return v.f;
}
__device__ __forceinline__ ushort f2bf(float f) {
  union { float f; unsigned int i; } v; v.f = f;
  unsigned int r = v.i + 0x7FFFu + ((v.i >> 16) & 1u);   // RNE
  return (ushort)(r >> 16);
}

// ---------------------------------------------------------------------------
// Runtime dtype detection. flags[0]=1 -> x/weights fp32 (else bf16).
// flags[1]=1 -> edges int64 (else int32).
// ---------------------------------------------------------------------------
__global__ void detect_kernel(const void* x1, const void* ei1, int* flags) {
  __shared__ int cnt_wild, cnt_oddnz;
  if (threadIdx.x == 0) { cnt_wild = 0; cnt_oddnz = 0; }
  __syncthreads();
  const ushort* xu = (const ushort*)x1;
  int wild = 0;
#pragma unroll
  for (int k = 0; k < 4; k++) {
    ushort u = xu[threadIdx.x * 4 + k];
    int ex = (u >> 7) & 0xFF;
    if (ex >= 0x90) wild++;
  }
  if (wild) atomicAdd(&cnt_wild, wild);
  const int* ii = (const int*)ei1;
  if (ii[threadIdx.x * 2 + 1] != 0) atomicAdd(&cnt_oddnz, 1);
  __syncthreads();
  if (threadIdx.x == 0) {
    flags[0] = (cnt_wild > 64) ? 1 : 0;
    flags[1] = (cnt_oddnz < 8) ? 1 : 0;
  }
}

// Zero accumulated state (ws is poisoned 0xAA before every timed call).
__global__ void init_kernel(int* cnt0, int* cnt1, float* t0, float* t1) {
  int i = blockIdx.x * blockDim.x + threadIdx.x;
  if (i < N_NODES) { cnt0[i] = 0; cnt1[i] = 0; t0[i] = 0.f; t1[i] = 0.f; }
}

// Canonicalize edge_index -> int32 AND fused dst-histogram with rank capture
// (measured r2/r3: 640K device atomics ~= 40 us; replication is worse, r4).
__global__ void cvt_ei_count_kernel(const void* e0, const void* e1,
                                    int* o0, int* o1,
                                    int* cnt0, int* cnt1,
                                    int* rank0, int* rank1, const int* flags) {
  int b = blockIdx.y;
  const void* e = b ? e1 : e0;
  int* o = b ? o1 : o0;
  int* cnt = b ? cnt1 : cnt0;
  int* rank = b ? rank1 : rank0;
  int i = blockIdx.x * 256 + threadIdx.x;
  if (i >= 2 * N_EDGES) return;
  int v = flags[1] ? (int)((const long long*)e)[i] : ((const int*)e)[i];
  o[i] = v;
  if (i >= N_EDGES) rank[i - N_EDGES] = atomicAdd(&cnt[v], 1);
}

// Canonicalize x -> bf16. 4 elems/thread, vectorized both paths.
__global__ void cvt_x_kernel(const void* x0, const void* x1v,
                             ushort* o0, ushort* o1, const int* flags) {
  const void* x = blockIdx.y ? x1v : x0;
  ushort* o = blockIdx.y ? o1 : o0;
  int i4 = (blockIdx.x * 256 + threadIdx.x) * 4;
  if (i4 >= N_NODES * HID) return;
  if (flags[0]) {
    float4 v = *(const float4*)((const float*)x + i4);
    ushort4 w; w.x = f2bf(v.x); w.y = f2bf(v.y); w.z = f2bf(v.z); w.w = f2bf(v.w);
    *(ushort4*)(o + i4) = w;
  } else {
    *(ushort4*)(o + i4) = *(const ushort4*)((const ushort*)x + i4);
  }
}

// Canonicalize all weights/biases -> one packed bf16 buffer.
// W1 and W2 are stored TRANSPOSED (Wt[n*256+k] = W[k*256+n]) so gemm's
// B-staging is a straight int4 copy (kills the 1.1e7 LDS bank conflicts the
// in-LDS scalar transpose caused -- r5 profile).
// Layout: W1t[0] W2t[65536] W3[131072] Wl[196608] b1[197888] b2[198144]
//         b3[198400] bl[198656]; total 198661 elems.
__global__ void cvt_w_kernel(const void* W1, const void* W2, const void* W3, const void* Wl,
                             const void* b1, const void* b2, const void* b3, const void* bl,
                             ushort* out, const int* flags) {
  int i = blockIdx.x * 256 + threadIdx.x;
  if (i >= 198661) return;
  const void* src; int off; bool tr = false;
  if (i < 65536)       { src = W1; off = 0; tr = true; }
  else if (i < 131072) { src = W2; off = 65536; tr = true; }
  else if (i < 196608) { src = W3; off = 131072; }
  else if (i < 197888) { src = Wl; off = 196608; }
  else if (i < 198144) { src = b1; off = 197888; }
  else if (i < 198400) { src = b2; off = 198144; }
  else if (i < 198656) { src = b3; off = 198400; }
  else                 { src = bl; off = 198656; }
  int j = i - off;
  if (tr) j = (j & 255) * 256 + (j >> 8);   // read W[k][n] for out index (n,k)
  out[i] = flags[0] ? f2bf(((const float*)src)[j]) : ((const ushort*)src)[j];
}

// Exclusive scan -> CSR row_ptr, fused with dinv = rsqrt(cnt+1).
__global__ __launch_bounds__(1024) void scan_kernel(const int* cnt0, const int* cnt1,
                                                    int* rp0, int* rp1,
                                                    float* dinv0, float* dinv1) {
  const int* cnt = blockIdx.x ? cnt1 : cnt0;
  int* rp = blockIdx.x ? rp1 : rp0;
  float* dinv = blockIdx.x ? dinv1 : dinv0;
  __shared__ int sd[1024];
  int tid = threadIdx.x;
  int base = tid * 20;
  int pref[20];
  int run = 0;
#pragma unroll
  for (int k = 0; k < 20; k++) {
    int i = base + k;
    int c = (i < N_NODES) ? cnt[i] : 0;
    if (i < N_NODES) dinv[i] = rsqrtf((float)c + 1.0f);
    run += c;
    pref[k] = run;
  }
  sd[tid] = run;
  __syncthreads();
  for (int off = 1; off < 1024; off <<= 1) {
    int v = (tid >= off) ? sd[tid - off] : 0;
    __syncthreads();
    sd[tid] += v;
    __syncthreads();
  }
  int offset = sd[tid] - run;
  if (tid == 0) rp[0] = 0;
#pragma unroll
  for (int k = 0; k < 20; k++) {
    int i = base + k;
    if (i < N_NODES) rp[i + 1] = offset + pref[k];
  }
}

// Fill CSR (packed (src,coef) int2) using precomputed rank (no slot atomic),
// plus t[src] += dinv[dst] (feeds layer-3 shortcut c_j = dinv_j*(t_j+dinv_j)).
__global__ void fill_kernel(const int* ei0, const int* ei1,
                            const float* dinv0, const float* dinv1,
                            const int* rp0, const int* rp1,
                            const int* rank0, const int* rank1,
                            int2* eg0, int2* eg1,
                            float* t0, float* t1) {
  int e = blockIdx.x * blockDim.x + threadIdx.x;
  if (e >= N_EDGES) return;
  int b = blockIdx.y;
  const int* ei = b ? ei1 : ei0;
  const float* dinv = b ? dinv1 : dinv0;
  const int* rp = b ? rp1 : rp0;
  const int* rank = b ? rank1 : rank0;
  int2* eg = b ? eg1 : eg0;
  float* t = b ? t1 : t0;
  int src = ei[e], dst = ei[N_EDGES + e];
  int slot = rp[dst] + rank[e];
  float dd = dinv[dst];
  eg[slot] = make_int2(src, __float_as_int(dinv[src] * dd));
  atomicAdd(&t[src], dd);
}

// C[M,256] = A[M,256] @ W[256,256] with W given TRANSPOSED (Wt[n][k]).
// Block 256 thr = 4 waves; 64x64 tile; BK=32; 16x16x32 bf16 MFMA.
__global__ __launch_bounds__(256) void gemm_kernel(
    const ushort* __restrict__ A0, const ushort* __restrict__ A1,
    const ushort* __restrict__ Wt,
    ushort* __restrict__ C0, ushort* __restrict__ C1) {
  const ushort* A = blockIdx.z ? A1 : A0;
  ushort* C = blockIdx.z ? C1 : C0;
  int m0 = blockIdx.x * 64;
  int n0 = blockIdx.y * 64;
  __shared__ ushort As[64][40];   // row stride 80 B (not pow2 -> <=2-way, free)
  __shared__ ushort Bs[64][40];   // Bs[n][k] = Wt[(n0+n)*256 + k0+k]
  int tid = threadIdx.x;
  int wave = tid >> 6, lane = tid & 63;
  int quad = lane >> 4, r16 = lane & 15;
  f32x4 acc0 = {0.f, 0.f, 0.f, 0.f}, acc1 = acc0, acc2 = acc0, acc3 = acc0;
  int l_row = tid >> 2;           // 0..63
  int l_off = (tid & 3) * 8;      // 0,8,16,24
  for (int k0 = 0; k0 < 256; k0 += 32) {
    int gr = m0 + l_row;
    int4 va = {0, 0, 0, 0};
    if (gr < N_NODES) va = *(const int4*)(A + gr * 256 + k0 + l_off);
    *(int4*)&As[l_row][l_off] = va;
    int4 vb = *(const int4*)(Wt + (n0 + l_row) * 256 + k0 + l_off);
    *(int4*)&Bs[l_row][l_off] = vb;
    __syncthreads();
    bf16x8 a  = *(const bf16x8*)&As[wave * 16 + r16][quad * 8];
    bf16x8 b0 = *(const bf16x8*)&Bs[r16][quad * 8];
    bf16x8 b1 = *(const bf16x8*)&Bs[16 + r16][quad * 8];
    bf16x8 b2 = *(const bf16x8*)&Bs[32 + r16][quad * 8];
    bf16x8 b3 = *(const bf16x8*)&Bs[48 + r16][quad * 8];
    acc0 = __builtin_amdgcn_mfma_f32_16x16x32_bf16(a, b0, acc0, 0, 0, 0);
    acc1 = __builtin_amdgcn_mfma_f32_16x16x32_bf16(a, b1, acc1, 0, 0, 0);
    acc2 = __builtin_amdgcn_mfma_f32_16x16x32_bf16(a, b2, acc2, 0, 0, 0);
    acc3 = __builtin_amdgcn_mfma_f32_16x16x32_bf16(a, b3, acc3, 0, 0, 0);
    __syncthreads();
  }
  int orow = m0 + wave * 16 + quad * 4;
#pragma unroll
  for (int r = 0; r < 4; r++) {
    int gr = orow + r;
    if (gr < N_NODES) {
      ushort* cp = C + gr * 256 + n0 + r16;
      cp[0]  = f2bf(acc0[r]);
      cp[16] = f2bf(acc1[r]);
      cp[32] = f2bf(acc2[r]);
      cp[48] = f2bf(acc3[r]);
    }
  }
}

// H[i] = relu( dinv_i^2 * XW[i] + sum_e coef_e * XW[col_e] + bias ).
// Wave split into two 32-lane halves; each half owns a DIFFERENT edge; lane
// owns 8 features (us8 = 16B b128 load -> one instr covers 2 edge-rows, 1KiB).
// Pair loop x4-unrolled => 8 edges in flight per wave (2x r5's MLP).
// Cross-half merge via one __shfl_xor(32) pass at the end.
__global__ __launch_bounds__(256) void agg_kernel(
    const ushort* __restrict__ XW0, const ushort* __restrict__ XW1,
    const float* __restrict__ dinv0, const float* __restrict__ dinv1,
    const int* __restrict__ rp0, const int* __restrict__ rp1,
    const int2* __restrict__ eg0, const int2* __restrict__ eg1,
    const ushort* __restrict__ bias,
    ushort* __restrict__ H0, ushort* __restrict__ H1) {
  int b = blockIdx.y;
  const ushort* XW = b ? XW1 : XW0;
  const float* dinv = b ? dinv1 : dinv0;
  const int* rp = b ? rp1 : rp0;
  const int2* eg = b ? eg1 : eg0;
  ushort* H = b ? H1 : H0;
  int wave = threadIdx.x >> 6, lane = threadIdx.x & 63;
  int half = lane >> 5;
  int fl = (lane & 31) * 8;               // 8 features per lane
  int i = blockIdx.x * 4 + wave;          // 20000 = 5000*4 exact
  float di = dinv[i];
  float selfw = half ? 0.f : di * di;     // self term only on half 0 (merged later)
  us8 v = *(const us8*)(XW + i * 256 + fl);
  float accA[8], accB[8];
#pragma unroll
  for (int j = 0; j < 8; j++) { accA[j] = selfw * bf2f(v[j]); accB[j] = 0.f; }
  int e0 = rp[i], e1 = rp[i + 1];
  int n = e1 - e0;
  int npair = n >> 1;
  int pe = 0;
  for (; pe + 3 < npair; pe += 4) {
    int ea = e0 + 2 * pe + half;
    int2 p0 = eg[ea];
    int2 p1 = eg[ea + 2];
    int2 p2 = eg[ea + 4];
    int2 p3 = eg[ea + 6];
    us8 r0 = *(const us8*)(XW + p0.x * 256 + fl);
    us8 r1 = *(const us8*)(XW + p1.x * 256 + fl);
    us8 r2 = *(const us8*)(XW + p2.x * 256 + fl);
    us8 r3 = *(const us8*)(XW + p3.x * 256 + fl);
    float w0 = __int_as_float(p0.y), w1 = __int_as_float(p1.y);
    float w2 = __int_as_float(p2.y), w3 = __int_as_float(p3.y);
#pragma unroll
    for (int j = 0; j < 8; j++) {
      accA[j] += w0 * bf2f(r0[j]);
      accB[j] += w1 * bf2f(r1[j]);
      accA[j] += w2 * bf2f(r2[j]);
      accB[j] += w3 * bf2f(r3[j]);
    }
  }
  for (; pe < npair; pe++) {
    int2 pp = eg[e0 + 2 * pe + half];
    us8 r = *(const us8*)(XW + pp.x * 256 + fl);
    float w = __int_as_float(pp.y);
#pragma unroll
    for (int j = 0; j < 8; j++) accA[j] += w * bf2f(r[j]);
  }
  if (n & 1) {                            // odd tail edge: half 0 only
    int2 pp = eg[e1 - 1];
    float w = half ? 0.f : __int_as_float(pp.y);
    us8 r = *(const us8*)(XW + pp.x * 256 + fl);
#pragma unroll
    for (int j = 0; j < 8; j++) accB[j] += w * bf2f(r[j]);
  }
  us8 bb = *(const us8*)(bias + fl);
  us8 o;
#pragma unroll
  for (int j = 0; j < 8; j++) {
    float s = accA[j] + accB[j];
    s += __shfl_xor(s, 32);               // merge the two halves
    o[j] = f2bf(fmaxf(s + bf2f(bb[j]), 0.f));
  }
  if (half == 0) *(us8*)(H + i * 256 + fl) = o;
}

// Partial column sums: wave w of block handles rows j = (blk*4+w) + 256*k.
__global__ __launch_bounds__(256) void colsum_kernel(
    const ushort* __restrict__ H0, const ushort* __restrict__ H1,
    const float* __restrict__ dinv0, const float* __restrict__ dinv1,
    const float* __restrict__ t0, const float* __restrict__ t1,
    float* __restrict__ P) {
  int b = blockIdx.y;
  const ushort* H = b ? H1 : H0;
  const float* dinv = b ? dinv1 : dinv0;
  const float* t = b ? t1 : t0;
  int wave = threadIdx.x >> 6, lane = threadIdx.x & 63;
  int wid = blockIdx.x * 4 + wave;        // 0..255
  int f4 = lane * 4;
  float a0 = 0.f, a1 = 0.f, a2 = 0.f, a3 = 0.f;
  for (int j = wid; j < N_NODES; j += 256) {
    float dj = dinv[j];
    float c = dj * (t[j] + dj);
    ushort4 u = *(const ushort4*)(H + j * 256 + f4);
    a0 += c * bf2f(u.x); a1 += c * bf2f(u.y);
    a2 += c * bf2f(u.z); a3 += c * bf2f(u.w);
  }
  __shared__ float part[4][256];
  part[wave][f4 + 0] = a0; part[wave][f4 + 1] = a1;
  part[wave][f4 + 2] = a2; part[wave][f4 + 3] = a3;
  __syncthreads();
  int f = threadIdx.x;
  float ssum = part[0][f] + part[1][f] + part[2][f] + part[3][f];
  P[(b * 64 + blockIdx.x) * 256 + f] = ssum;
}

// s = reduce partials; pooled = ((s0+s1)@W3)/(2N)+b3 ; out = pooled@Wl + bl
__global__ __launch_bounds__(256) void final_kernel(
    const float* __restrict__ P,
    const ushort* __restrict__ W3, const ushort* __restrict__ b3,
    const ushort* __restrict__ Wl, const ushort* __restrict__ bl,
    void* __restrict__ out, const int* __restrict__ flags) {
  __shared__ float v[256];
  __shared__ float pooled[256];
  int t = threadIdx.x;
  float acc0 = 0.f, acc1 = 0.f;
  for (int b = 0; b < 64; b++) {
    acc0 += P[b * 256 + t];
    acc1 += P[(64 + b) * 256 + t];
  }
  v[t] = acc0 + acc1;
  __syncthreads();
  float acc = 0.f;
  for (int f = 0; f < 256; f++) acc += v[f] * bf2f(W3[f * 256 + t]);
  pooled[t] = acc * (1.0f / (2.0f * N_NODES)) + bf2f(b3[t]);
  __syncthreads();
  if (t < 5) {
    float o = bf2f(bl[t]);
    for (int h = 0; h < 256; h++) o += pooled[h] * bf2f(Wl[h * 5 + t]);
    if (flags[0]) ((float*)out)[t] = o;
    else ((ushort*)out)[t] = f2bf(o);
  }
}

extern "C" void kernel_launch(void* const* d_in, const int* in_sizes, int n_in,
                              void* d_out, int out_size, void* d_ws, size_t ws_size,
                              hipStream_t stream) {
  const void* x1 = d_in[0];
  const void* ei1 = d_in[1];
  const void* x2 = d_in[2];
  const void* ei2 = d_in[3];
  const void* W1 = d_in[4];
  const void* b1 = d_in[5];
  const void* W2 = d_in[6];
  const void* b2 = d_in[7];
  const void* W3 = d_in[8];
  const void* b3 = d_in[9];
  const void* Wl = d_in[10];
  const void* bl = d_in[11];

  char* p = (char*)d_ws;
  auto alloc = [&](size_t bytes) {
    char* r = p;
    p += (bytes + 255) & ~size_t(255);
    return r;
  };
  int* flags   = (int*)alloc(256);
  float* dinv0 = (float*)alloc(N_NODES * 4);
  float* dinv1 = (float*)alloc(N_NODES * 4);
  float* t0    = (float*)alloc(N_NODES * 4);
  float* t1    = (float*)alloc(N_NODES * 4);
  int* cnt0    = (int*)alloc(N_NODES * 4);
  int* cnt1    = (int*)alloc(N_NODES * 4);
  int* rp0     = (int*)alloc((N_NODES + 1) * 4);
  int* rp1     = (int*)alloc((N_NODES + 1) * 4);
  int2* eg0    = (int2*)alloc((size_t)N_EDGES * 8);
  int2* eg1    = (int2*)alloc((size_t)N_EDGES * 8);
  float* Pp    = (float*)alloc(2 * 64 * 256 * 4);
  ushort* wbuf = (ushort*)alloc(198661 * 2);
  ushort* xw0  = (ushort*)alloc((size_t)N_NODES * HID * 2);
  ushort* xw1  = (ushort*)alloc((size_t)N_NODES * HID * 2);
  ushort* xc0  = (ushort*)alloc((size_t)N_NODES * HID * 2);
  ushort* xc1  = (ushort*)alloc((size_t)N_NODES * HID * 2);
  // Lifetime aliasing: ei32+rank live only until fill_kernel; xw0 is first
  // written by gemm1 (after fill). 2*2.56 + 2*1.28 = 7.7MB <= 10.24MB.
  int* ei32_0 = (int*)xw0;
  int* ei32_1 = ei32_0 + 2 * N_EDGES;
  int* rank0  = ei32_1 + 2 * N_EDGES;
  int* rank1  = rank0 + N_EDGES;
  // xc dead after gemm1 reads it; h first written by agg1 (after gemm1).
  ushort* h0 = xc0;
  ushort* h1 = xc1;

  ushort* Wc1 = wbuf + 0;        // transposed
  ushort* Wc2 = wbuf + 65536;    // transposed
  ushort* Wc3 = wbuf + 131072;
  ushort* Wlc = wbuf + 196608;
  ushort* bc1 = wbuf + 197888;
  ushort* bc2 = wbuf + 198144;
  ushort* bc3 = wbuf + 198400;
  ushort* blc = wbuf + 198656;

  // --- dtype detection + canonicalization + graph prep ---
  detect_kernel<<<1, 256, 0, stream>>>(x1, ei1, flags);
  init_kernel<<<(N_NODES + 255) / 256, 256, 0, stream>>>(cnt0, cnt1, t0, t1);
  cvt_ei_count_kernel<<<dim3((2 * N_EDGES + 255) / 256, 2), 256, 0, stream>>>(
      ei1, ei2, ei32_0, ei32_1, cnt0, cnt1, rank0, rank1, flags);
  cvt_x_kernel<<<dim3(N_NODES * HID / 1024, 2), 256, 0, stream>>>(
      x1, x2, xc0, xc1, flags);
  cvt_w_kernel<<<(198661 + 255) / 256, 256, 0, stream>>>(
      W1, W2, W3, Wl, b1, b2, b3, bl, wbuf, flags);
  scan_kernel<<<2, 1024, 0, stream>>>(cnt0, cnt1, rp0, rp1, dinv0, dinv1);
  fill_kernel<<<dim3((N_EDGES + 255) / 256, 2), 256, 0, stream>>>(
      ei32_0, ei32_1, dinv0, dinv1, rp0, rp1, rank0, rank1, eg0, eg1, t0, t1);

  // Layer 1: xw = x @ W1 ; h = relu(agg(xw) + b1)
  gemm_kernel<<<dim3(313, 4, 2), 256, 0, stream>>>(xc0, xc1, Wc1, xw0, xw1);
  agg_kernel<<<dim3(N_NODES / 4, 2), 256, 0, stream>>>(
      xw0, xw1, dinv0, dinv1, rp0, rp1, eg0, eg1, bc1, h0, h1);

  // Layer 2: xw = h @ W2 ; h = relu(agg(xw) + b2)
  gemm_kernel<<<dim3(313, 4, 2), 256, 0, stream>>>(h0, h1, Wc2, xw0, xw1);
  agg_kernel<<<dim3(N_NODES / 4, 2), 256, 0, stream>>>(
      xw0, xw1, dinv0, dinv1, rp0, rp1, eg0, eg1, bc2, h0, h1);

  // Layer 3 + pool collapsed: s = sum_j c_j h2_j ; out = ((s0+s1)W3/(2N)+b3)@Wl+bl
  colsum_kernel<<<dim3(64, 2), 256, 0, stream>>>(h0, h1, dinv0, dinv1, t0, t1, Pp);
  final_kernel<<<1, 256, 0, stream>>>(Pp, Wc3, bc3, Wlc, blc, d_out, flags);
}